// Round 2
// baseline (594.106 us; speedup 1.0000x reference)
//
#include <hip/hip_runtime.h>
#include <hip/hip_bf16.h>

#define NTOK 16384
#define HDIM 2048
#define NEXP 128
#define KSEL 8

#define BM 64
#define BK 32
#define BSTRIDE (BK + 4)   // 36 floats: keeps 16B alignment, breaks pow2 bank stride

// ---------------------------------------------------------------------------
// Fused router: logits = x @ W^T with fp64 accumulation (ranking must match
// the fp64 numpy reference; fp32 ranking flips near-ties), then in-block
// softmax + top-8 + renormalize on the fp64 values.
//
// block 256 = 16(tn) x 16(tm); per-thread 4 tokens x 8 experts (fp64 acc).
// The 16 threads sharing tm are contiguous lanes of one wave and jointly hold
// all 128 experts of their 4 tokens -> top-k via __shfl_xor width=16.
// ---------------------------------------------------------------------------
__global__ __launch_bounds__(256) void router_fused(
    const float* __restrict__ x,
    const float* __restrict__ w,
    float* __restrict__ logits,
    float* __restrict__ topv,
    float* __restrict__ topi)
{
    __shared__ float Bs[NEXP][BSTRIDE];

    const int tid = threadIdx.x;
    const int tn  = tid & 15;
    const int tm  = tid >> 4;
    const int row0 = blockIdx.x * BM;

    // W staging mapping: 8 lanes per row segment -> 128B coalesced reads
    const int kc = tid & 7;
    const int cr = tid >> 3;

    double acc[4][8];
#pragma unroll
    for (int i = 0; i < 4; ++i)
#pragma unroll
        for (int j = 0; j < 8; ++j) acc[i][j] = 0.0;

    const float* xp[4];
#pragma unroll
    for (int i = 0; i < 4; ++i)
        xp[i] = x + (size_t)(row0 + tm + 16 * i) * HDIM;

    // prologue: prefetch W tile 0 into registers
    float4 rb[4];
#pragma unroll
    for (int p = 0; p < 4; ++p)
        rb[p] = *reinterpret_cast<const float4*>(&w[(size_t)(cr + 32 * p) * HDIM + kc * 4]);

    for (int k0 = 0; k0 < HDIM; k0 += BK) {
        __syncthreads();
#pragma unroll
        for (int p = 0; p < 4; ++p)
            *reinterpret_cast<float4*>(&Bs[cr + 32 * p][kc * 4]) = rb[p];
        __syncthreads();

        if (k0 + BK < HDIM) {
#pragma unroll
            for (int p = 0; p < 4; ++p)
                rb[p] = *reinterpret_cast<const float4*>(
                    &w[(size_t)(cr + 32 * p) * HDIM + (k0 + BK) + kc * 4]);
        }

#pragma unroll 4
        for (int k4 = 0; k4 < BK; k4 += 4) {
            float4 a4[4], b4[8];
#pragma unroll
            for (int i = 0; i < 4; ++i)
                a4[i] = *reinterpret_cast<const float4*>(&xp[i][k0 + k4]);
#pragma unroll
            for (int j = 0; j < 8; ++j)
                b4[j] = *reinterpret_cast<const float4*>(&Bs[tn + 16 * j][k4]);

#pragma unroll
            for (int kk = 0; kk < 4; ++kk) {
                double bd[8];
#pragma unroll
                for (int j = 0; j < 8; ++j)
                    bd[j] = (double)((const float*)&b4[j])[kk];
#pragma unroll
                for (int i = 0; i < 4; ++i) {
                    const double ad = (double)((const float*)&a4[i])[kk];
#pragma unroll
                    for (int j = 0; j < 8; ++j)
                        acc[i][j] = fma(ad, bd[j], acc[i][j]);
                }
            }
        }
    }

    // ---- logits (fp32 narrow; threshold is loose) ----
#pragma unroll
    for (int i = 0; i < 4; ++i) {
        float* orow = logits + (size_t)(row0 + tm + 16 * i) * NEXP;
#pragma unroll
        for (int j = 0; j < 8; ++j)
            orow[tn + 16 * j] = (float)acc[i][j];
    }

    // ---- fused softmax + top-8 on fp64 values ----
    for (int i = 0; i < 4; ++i) {
        const int t = row0 + tm + 16 * i;
        unsigned sel = 0u;
        double m = 0.0;          // rank-1 value (set at k=0)
        double kv = 0.0;         // lane tn==k stashes rank-k value
        int    ki = 0;
        const double NEGD = -__builtin_inf();

#pragma unroll
        for (int k = 0; k < KSEL; ++k) {
            // local argmax among unselected (ascending j + strict > => lowest
            // expert id wins ties; expert id = tn + 16*j is monotone in j)
            double lv = NEGD;
            int    le = 0;
#pragma unroll
            for (int j = 0; j < 8; ++j) {
                const double v = (sel >> j) & 1u ? NEGD : acc[i][j];
                if (v > lv) { lv = v; le = tn + 16 * j; }
            }
            double cv = lv; int ce = le;
#pragma unroll
            for (int off = 8; off > 0; off >>= 1) {
                const double ov = __shfl_xor(cv, off, 16);
                const int    oe = __shfl_xor(ce, off, 16);
                if (ov > cv || (ov == cv && oe < ce)) { cv = ov; ce = oe; }
            }
            if (k == 0) m = cv;
            if (tn == k) { kv = cv; ki = ce; }
            if ((ce & 15) == tn) sel |= 1u << (ce >> 4);   // owner marks selected
        }

        // softmax denominator over all 128 experts (fp32 exp is plenty here)
        float z = 0.0f;
#pragma unroll
        for (int j = 0; j < 8; ++j)
            z += expf((float)(acc[i][j] - m));
#pragma unroll
        for (int off = 8; off > 0; off >>= 1)
            z += __shfl_xor(z, off, 16);

        const float p = (tn < KSEL) ? expf((float)(kv - m)) / z : 0.0f;
        float ps = p;
#pragma unroll
        for (int off = 8; off > 0; off >>= 1)
            ps += __shfl_xor(ps, off, 16);

        if (tn < KSEL) {
            topv[(size_t)t * KSEL + tn] = p / ps;
            topi[(size_t)t * KSEL + tn] = (float)ki;
        }
    }
}

extern "C" void kernel_launch(void* const* d_in, const int* in_sizes, int n_in,
                              void* d_out, int out_size, void* d_ws, size_t ws_size,
                              hipStream_t stream) {
    const float* x = (const float*)d_in[0];   // [16384, 2048]
    const float* w = (const float*)d_in[1];   // [128, 2048]

    float* out    = (float*)d_out;
    float* logits = out;                                   // 16384*128
    float* topv   = out + (size_t)NTOK * NEXP;             // 16384*8
    float* topi   = topv + (size_t)NTOK * KSEL;            // 16384*8

    router_fused<<<NTOK / BM, 256, 0, stream>>>(x, w, logits, topv, topi);
}

// Round 3
// 362.850 us; speedup vs baseline: 1.6373x; 1.6373x over previous
//
#include <hip/hip_runtime.h>
#include <hip/hip_bf16.h>

#define NTOK 16384
#define HDIM 2048
#define NEXP 128
#define KSEL 8

#define BM 64
#define BK 32
#define BSTRIDE (BK + 4)   // 36 floats: keeps 16B alignment, breaks pow2 bank stride

// ---------------------------------------------------------------------------
// Split-K fp64 GEMM: part[kc][t][e] = x[t, kc*KC:(kc+1)*KC] @ W[e, same]^T
// block 256 = 16(tn) x 16(tm); per-thread 4 tokens x 8 experts (fp64 acc).
// W tile staged in LDS (register double-buffered); x loads register
// double-buffered (prefetch k4+4 before the FMA block for k4).
// ---------------------------------------------------------------------------
template <int SPLITK>
__global__ __launch_bounds__(256) void router_gemm_sk(
    const float* __restrict__ x,
    const float* __restrict__ w,
    double* __restrict__ part)
{
    __shared__ float Bs[NEXP][BSTRIDE];
    constexpr int KC = HDIM / SPLITK;

    const int tid = threadIdx.x;
    const int tn  = tid & 15;
    const int tm  = tid >> 4;
    const int row0  = blockIdx.x * BM;
    const int kbase = blockIdx.y * KC;

    // W staging mapping: 8 lanes per row segment -> 128B coalesced reads
    const int skc = tid & 7;
    const int scr = tid >> 3;

    double acc[4][8];
#pragma unroll
    for (int i = 0; i < 4; ++i)
#pragma unroll
        for (int j = 0; j < 8; ++j) acc[i][j] = 0.0;

    const float* xp[4];
#pragma unroll
    for (int i = 0; i < 4; ++i)
        xp[i] = x + (size_t)(row0 + tm + 16 * i) * HDIM + kbase;

    // prologue: prefetch W tile 0 and first x quad
    float4 rb[4];
#pragma unroll
    for (int p = 0; p < 4; ++p)
        rb[p] = *reinterpret_cast<const float4*>(
            &w[(size_t)(scr + 32 * p) * HDIM + kbase + skc * 4]);

    float4 a_cur[4];
#pragma unroll
    for (int i = 0; i < 4; ++i)
        a_cur[i] = *reinterpret_cast<const float4*>(&xp[i][0]);

    for (int k0 = 0; k0 < KC; k0 += BK) {
        __syncthreads();
#pragma unroll
        for (int p = 0; p < 4; ++p)
            *reinterpret_cast<float4*>(&Bs[scr + 32 * p][skc * 4]) = rb[p];
        __syncthreads();

        if (k0 + BK < KC) {
#pragma unroll
            for (int p = 0; p < 4; ++p)
                rb[p] = *reinterpret_cast<const float4*>(
                    &w[(size_t)(scr + 32 * p) * HDIM + kbase + (k0 + BK) + skc * 4]);
        }

#pragma unroll 4
        for (int k4 = 0; k4 < BK; k4 += 4) {
            float4 a4[4];
#pragma unroll
            for (int i = 0; i < 4; ++i) a4[i] = a_cur[i];

            // prefetch next x quad (overlaps the FMA block below)
            const int knext = k0 + k4 + 4;
            if (knext < KC) {
#pragma unroll
                for (int i = 0; i < 4; ++i)
                    a_cur[i] = *reinterpret_cast<const float4*>(&xp[i][knext]);
            }

            float4 b4[8];
#pragma unroll
            for (int j = 0; j < 8; ++j)
                b4[j] = *reinterpret_cast<const float4*>(&Bs[tn + 16 * j][k4]);

#pragma unroll
            for (int kk = 0; kk < 4; ++kk) {
                double bd[8];
#pragma unroll
                for (int j = 0; j < 8; ++j)
                    bd[j] = (double)((const float*)&b4[j])[kk];
#pragma unroll
                for (int i = 0; i < 4; ++i) {
                    const double ad = (double)((const float*)&a4[i])[kk];
#pragma unroll
                    for (int j = 0; j < 8; ++j)
                        acc[i][j] = fma(ad, bd[j], acc[i][j]);
                }
            }
        }
    }

    double* pbase = part + (size_t)blockIdx.y * NTOK * NEXP;
#pragma unroll
    for (int i = 0; i < 4; ++i) {
        double* pr = pbase + (size_t)(row0 + tm + 16 * i) * NEXP;
#pragma unroll
        for (int j = 0; j < 8; ++j)
            pr[tn + 16 * j] = acc[i][j];
    }
}

// ---------------------------------------------------------------------------
// Reduce split-K fp64 partials (fixed order -> deterministic, err ~1e-16 <<
// min ranking gap ~3e-7), then softmax + top-8 + renormalize.
// One wave per token; lane owns experts {2*lane, 2*lane+1}.
// ---------------------------------------------------------------------------
__global__ __launch_bounds__(256) void router_reduce_topk(
    const double* __restrict__ part, int splitk,
    float* __restrict__ logits,
    float* __restrict__ topv,
    float* __restrict__ topi)
{
    const int lane = threadIdx.x & 63;
    const int t = (int)((blockIdx.x * 256u + threadIdx.x) >> 6);

    const size_t stride = (size_t)NTOK * NEXP;
    const double* p0 = part + (size_t)t * NEXP + lane * 2;

    double v0 = 0.0, v1 = 0.0;
    for (int kc = 0; kc < splitk; ++kc) {
        const double2 d = *reinterpret_cast<const double2*>(p0 + kc * stride);
        v0 += d.x;
        v1 += d.y;
    }

    // logits output (fp32 narrow; threshold is loose)
    *reinterpret_cast<float2*>(logits + (size_t)t * NEXP + lane * 2) =
        make_float2((float)v0, (float)v1);

    const int e0 = lane * 2, e1 = lane * 2 + 1;
    bool s0 = false, s1 = false;
    double m = 0.0, kv = 0.0;
    int ki = 0;
    const double NEGD = -__builtin_inf();

#pragma unroll
    for (int k = 0; k < KSEL; ++k) {
        const double c0 = s0 ? NEGD : v0;
        const double c1 = s1 ? NEGD : v1;
        double cv; int ce;
        if (c0 >= c1) { cv = c0; ce = e0; }   // lower expert id wins ties
        else          { cv = c1; ce = e1; }
#pragma unroll
        for (int off = 32; off > 0; off >>= 1) {
            const double ov = __shfl_xor(cv, off);
            const int    oe = __shfl_xor(ce, off);
            if (ov > cv || (ov == cv && oe < ce)) { cv = ov; ce = oe; }
        }
        if (k == 0) m = cv;
        if (lane == k) { kv = cv; ki = ce; }
        if (ce == e0) s0 = true;
        if (ce == e1) s1 = true;
    }

    // softmax denominator over all 128 experts
    float z = expf((float)(v0 - m)) + expf((float)(v1 - m));
#pragma unroll
    for (int off = 32; off > 0; off >>= 1)
        z += __shfl_xor(z, off);

    const float p = (lane < KSEL) ? expf((float)(kv - m)) / z : 0.0f;
    float ps = p;
#pragma unroll
    for (int off = 32; off > 0; off >>= 1)
        ps += __shfl_xor(ps, off);

    if (lane < KSEL) {
        topv[(size_t)t * KSEL + lane] = p / ps;
        topi[(size_t)t * KSEL + lane] = (float)ki;
    }
}

// ---------------------------------------------------------------------------
// Fallback: the proven round-2 fused kernel (used only if ws_size is too
// small for even split-K=1 partials).
// ---------------------------------------------------------------------------
__global__ __launch_bounds__(256) void router_fused(
    const float* __restrict__ x,
    const float* __restrict__ w,
    float* __restrict__ logits,
    float* __restrict__ topv,
    float* __restrict__ topi)
{
    __shared__ float Bs[NEXP][BSTRIDE];

    const int tid = threadIdx.x;
    const int tn  = tid & 15;
    const int tm  = tid >> 4;
    const int row0 = blockIdx.x * BM;
    const int kc = tid & 7;
    const int cr = tid >> 3;

    double acc[4][8];
#pragma unroll
    for (int i = 0; i < 4; ++i)
#pragma unroll
        for (int j = 0; j < 8; ++j) acc[i][j] = 0.0;

    const float* xp[4];
#pragma unroll
    for (int i = 0; i < 4; ++i)
        xp[i] = x + (size_t)(row0 + tm + 16 * i) * HDIM;

    float4 rb[4];
#pragma unroll
    for (int p = 0; p < 4; ++p)
        rb[p] = *reinterpret_cast<const float4*>(&w[(size_t)(cr + 32 * p) * HDIM + kc * 4]);

    for (int k0 = 0; k0 < HDIM; k0 += BK) {
        __syncthreads();
#pragma unroll
        for (int p = 0; p < 4; ++p)
            *reinterpret_cast<float4*>(&Bs[cr + 32 * p][kc * 4]) = rb[p];
        __syncthreads();

        if (k0 + BK < HDIM) {
#pragma unroll
            for (int p = 0; p < 4; ++p)
                rb[p] = *reinterpret_cast<const float4*>(
                    &w[(size_t)(cr + 32 * p) * HDIM + (k0 + BK) + kc * 4]);
        }

#pragma unroll 4
        for (int k4 = 0; k4 < BK; k4 += 4) {
            float4 a4[4], b4[8];
#pragma unroll
            for (int i = 0; i < 4; ++i)
                a4[i] = *reinterpret_cast<const float4*>(&xp[i][k0 + k4]);
#pragma unroll
            for (int j = 0; j < 8; ++j)
                b4[j] = *reinterpret_cast<const float4*>(&Bs[tn + 16 * j][k4]);
#pragma unroll
            for (int kk = 0; kk < 4; ++kk) {
                double bd[8];
#pragma unroll
                for (int j = 0; j < 8; ++j)
                    bd[j] = (double)((const float*)&b4[j])[kk];
#pragma unroll
                for (int i = 0; i < 4; ++i) {
                    const double ad = (double)((const float*)&a4[i])[kk];
#pragma unroll
                    for (int j = 0; j < 8; ++j)
                        acc[i][j] = fma(ad, bd[j], acc[i][j]);
                }
            }
        }
    }

#pragma unroll
    for (int i = 0; i < 4; ++i) {
        float* orow = logits + (size_t)(row0 + tm + 16 * i) * NEXP;
#pragma unroll
        for (int j = 0; j < 8; ++j)
            orow[tn + 16 * j] = (float)acc[i][j];
    }

    for (int i = 0; i < 4; ++i) {
        const int t = row0 + tm + 16 * i;
        unsigned sel = 0u;
        double m = 0.0, kv = 0.0;
        int ki = 0;
        const double NEGD = -__builtin_inf();

#pragma unroll
        for (int k = 0; k < KSEL; ++k) {
            double lv = NEGD;
            int    le = 0;
#pragma unroll
            for (int j = 0; j < 8; ++j) {
                const double v = (sel >> j) & 1u ? NEGD : acc[i][j];
                if (v > lv) { lv = v; le = tn + 16 * j; }
            }
            double cv = lv; int ce = le;
#pragma unroll
            for (int off = 8; off > 0; off >>= 1) {
                const double ov = __shfl_xor(cv, off, 16);
                const int    oe = __shfl_xor(ce, off, 16);
                if (ov > cv || (ov == cv && oe < ce)) { cv = ov; ce = oe; }
            }
            if (k == 0) m = cv;
            if (tn == k) { kv = cv; ki = ce; }
            if ((ce & 15) == tn) sel |= 1u << (ce >> 4);
        }

        float z = 0.0f;
#pragma unroll
        for (int j = 0; j < 8; ++j)
            z += expf((float)(acc[i][j] - m));
#pragma unroll
        for (int off = 8; off > 0; off >>= 1)
            z += __shfl_xor(z, off, 16);

        const float p = (tn < KSEL) ? expf((float)(kv - m)) / z : 0.0f;
        float ps = p;
#pragma unroll
        for (int off = 8; off > 0; off >>= 1)
            ps += __shfl_xor(ps, off, 16);

        if (tn < KSEL) {
            topv[(size_t)t * KSEL + tn] = p / ps;
            topi[(size_t)t * KSEL + tn] = (float)ki;
        }
    }
}

extern "C" void kernel_launch(void* const* d_in, const int* in_sizes, int n_in,
                              void* d_out, int out_size, void* d_ws, size_t ws_size,
                              hipStream_t stream) {
    const float* x = (const float*)d_in[0];   // [16384, 2048]
    const float* w = (const float*)d_in[1];   // [128, 2048]

    float* out    = (float*)d_out;
    float* logits = out;                                   // 16384*128
    float* topv   = out + (size_t)NTOK * NEXP;             // 16384*8
    float* topi   = topv + (size_t)NTOK * KSEL;            // 16384*8

    double* part = (double*)d_ws;
    const size_t need1 = (size_t)NTOK * NEXP * sizeof(double);  // 16.8 MB

    if (ws_size >= 4 * need1) {
        router_gemm_sk<4><<<dim3(NTOK / BM, 4), 256, 0, stream>>>(x, w, part);
        router_reduce_topk<<<NTOK / 4, 256, 0, stream>>>(part, 4, logits, topv, topi);
    } else if (ws_size >= 2 * need1) {
        router_gemm_sk<2><<<dim3(NTOK / BM, 2), 256, 0, stream>>>(x, w, part);
        router_reduce_topk<<<NTOK / 4, 256, 0, stream>>>(part, 2, logits, topv, topi);
    } else if (ws_size >= need1) {
        router_gemm_sk<1><<<dim3(NTOK / BM, 1), 256, 0, stream>>>(x, w, part);
        router_reduce_topk<<<NTOK / 4, 256, 0, stream>>>(part, 1, logits, topv, topi);
    } else {
        router_fused<<<NTOK / BM, 256, 0, stream>>>(x, w, logits, topv, topi);
    }
}

// Round 4
// 154.113 us; speedup vs baseline: 3.8550x; 2.3544x over previous
//
#include <hip/hip_runtime.h>
#include <hip/hip_bf16.h>
#include <hip/hip_fp16.h>

#define NTOK 16384
#define HDIM 2048
#define NEXP 128
#define KSEL 8
#define NCAND 16

typedef _Float16 half8 __attribute__((ext_vector_type(8)));
typedef _Float16 half4v __attribute__((ext_vector_type(4)));
typedef float f32x4 __attribute__((ext_vector_type(4)));

// ===========================================================================
// Kernel 1: fp16 MFMA GEMM (logits, fp32 out) + per-token top-16 candidate
// selection. Grid 256 blocks x 256 thr (4 waves). Block = 64 tokens x 128
// experts, K staged in steps of 64. LDS is FRAGMENT-MAJOR: lane l's 16B MFMA
// fragment sits at l*16 (conflict-free ds_read_b128). A and B staged with the
// SAME k-mapping, so any mismatch vs the HW input layout is a k-permutation
// inside the dot product -> value-exact.
// ===========================================================================
__global__ __launch_bounds__(256) void gemm_select(
    const float* __restrict__ x,
    const float* __restrict__ w,
    float* __restrict__ logits,
    int* __restrict__ cand)
{
    __shared__ _Float16 sm[2 * 12288];   // 2 buffers x 24KB

    const int tid = threadIdx.x;
    const int l   = tid & 63;
    const int wv  = tid >> 6;
    const int t0  = blockIdx.x * 64;

    // ---- staging maps ----
    // x: thread covers token tl = tid>>2, k-quads kq[p] = 4*(tid&3) + 16*p
    const int tl = tid >> 2;
    const float* xrow = x + (size_t)(t0 + tl) * HDIM;
    int kqx[4], idxX[4];
#pragma unroll
    for (int p = 0; p < 4; ++p) {
        const int k = 4 * (tid & 3) + 16 * p;
        kqx[p] = k;
        idxX[p] = (tl >> 4) * 1024 + (k >> 5) * 512
                + ((tl & 15) + 16 * ((k >> 3) & 3)) * 8 + (k & 7);
    }
    // W: thread covers expert e = tid>>1, k-quads 4*(tid&1) + 8*q
    const int e = tid >> 1;
    const float* wrow = w + (size_t)e * HDIM;
    int kqw[8], idxW[8];
#pragma unroll
    for (int q = 0; q < 8; ++q) {
        const int k = 4 * (tid & 1) + 8 * q;
        kqw[q] = k;
        idxW[q] = 4096 + (e >> 4) * 1024 + (k >> 5) * 512
                + ((e & 15) + 16 * ((k >> 3) & 3)) * 8 + (k & 7);
    }

    f32x4 acc[8];
#pragma unroll
    for (int f = 0; f < 8; ++f) acc[f] = (f32x4){0.f, 0.f, 0.f, 0.f};

    f32x4 xa[4], xb[4], wr[8];
    // prologue: xa <- step 0, wr <- step 0, xb <- step 1
#pragma unroll
    for (int p = 0; p < 4; ++p) xa[p] = *reinterpret_cast<const f32x4*>(xrow + kqx[p]);
#pragma unroll
    for (int q = 0; q < 8; ++q) wr[q] = *reinterpret_cast<const f32x4*>(wrow + kqw[q]);
#pragma unroll
    for (int p = 0; p < 4; ++p) xb[p] = *reinterpret_cast<const f32x4*>(xrow + 64 + kqx[p]);

#define STEP(SV, XR)                                                            \
    {                                                                           \
        _Float16* sb = &sm[((SV) & 1) * 12288];                                 \
        _Pragma("unroll")                                                       \
        for (int p = 0; p < 4; ++p) {                                           \
            half4v hv = {(_Float16)XR[p][0], (_Float16)XR[p][1],                \
                         (_Float16)XR[p][2], (_Float16)XR[p][3]};               \
            *reinterpret_cast<half4v*>(&sb[idxX[p]]) = hv;                      \
        }                                                                       \
        _Pragma("unroll")                                                       \
        for (int q = 0; q < 8; ++q) {                                           \
            half4v hv = {(_Float16)wr[q][0], (_Float16)wr[q][1],                \
                         (_Float16)wr[q][2], (_Float16)wr[q][3]};               \
            *reinterpret_cast<half4v*>(&sb[idxW[q]]) = hv;                      \
        }                                                                       \
        if ((SV) + 1 < 32) {                                                    \
            const int kb = ((SV) + 1) * 64;                                     \
            _Pragma("unroll")                                                   \
            for (int q = 0; q < 8; ++q)                                         \
                wr[q] = *reinterpret_cast<const f32x4*>(wrow + kb + kqw[q]);    \
        }                                                                       \
        if ((SV) + 2 < 32) {                                                    \
            const int kb = ((SV) + 2) * 64;                                     \
            _Pragma("unroll")                                                   \
            for (int p = 0; p < 4; ++p)                                         \
                XR[p] = *reinterpret_cast<const f32x4*>(xrow + kb + kqx[p]);    \
        }                                                                       \
        __syncthreads();                                                        \
        const _Float16* xb_ = &sb[wv * 1024 + l * 8];                           \
        const _Float16* wb_ = &sb[4096 + l * 8];                                \
        _Pragma("unroll")                                                       \
        for (int kh = 0; kh < 2; ++kh) {                                        \
            half8 af = *reinterpret_cast<const half8*>(xb_ + kh * 512);         \
            _Pragma("unroll")                                                   \
            for (int f = 0; f < 8; ++f) {                                       \
                half8 bf = *reinterpret_cast<const half8*>(wb_ + f * 1024 + kh * 512); \
                acc[f] = __builtin_amdgcn_mfma_f32_16x16x32_f16(af, bf, acc[f], 0, 0, 0); \
            }                                                                   \
        }                                                                       \
        __syncthreads();                                                        \
    }

    for (int s = 0; s < 32; s += 2) {
        STEP(s, xa)
        STEP(s + 1, xb)
    }
#undef STEP

    // ---- logits store: D col = lane&15 (expert), row = 4*(lane>>4)+reg (token) ----
    const int grp = l >> 4;
#pragma unroll
    for (int f = 0; f < 8; ++f)
#pragma unroll
        for (int r = 0; r < 4; ++r) {
            const int t = t0 + wv * 16 + 4 * grp + r;
            logits[(size_t)t * NEXP + 16 * f + (l & 15)] = acc[f][r];
        }

    // ---- top-16 candidate selection per token (width-16 shuffle groups) ----
    const float NEG = -__builtin_inff();
#pragma unroll
    for (int r = 0; r < 4; ++r) {
        const int t = t0 + wv * 16 + 4 * grp + r;
        float v[8];
#pragma unroll
        for (int f = 0; f < 8; ++f) v[f] = acc[f][r];
        unsigned selm = 0u;
        int mycand = 0;
#pragma unroll
        for (int k = 0; k < NCAND; ++k) {
            float lv = NEG; int le = 0;
#pragma unroll
            for (int f = 0; f < 8; ++f) {
                const float c = ((selm >> f) & 1u) ? NEG : v[f];
                if (c > lv) { lv = c; le = 16 * f + (l & 15); }  // asc f => lower id on tie
            }
            float cv = lv; int ce = le;
#pragma unroll
            for (int off = 8; off > 0; off >>= 1) {
                const float ov = __shfl_xor(cv, off, 16);
                const int   oe = __shfl_xor(ce, off, 16);
                if (ov > cv || (ov == cv && oe < ce)) { cv = ov; ce = oe; }
            }
            if ((l & 15) == k) mycand = ce;
            if ((ce & 15) == (l & 15)) selm |= 1u << (ce >> 4);
        }
        cand[(size_t)t * NCAND + (l & 15)] = mycand;
    }
}

// ===========================================================================
// Kernel 2: fp64 refine of the 16 candidates + exact top-8 + normalized probs.
// One wave per token. x row register-resident (read once); W rows streamed
// (L2-resident, 1 MB total). Full-softmax denominator cancels in the
// renormalization, so only the 16 refined logits are needed.
// ===========================================================================
__global__ __launch_bounds__(256) void refine_topk(
    const float* __restrict__ x,
    const float* __restrict__ w,
    const int* __restrict__ cand,
    float* __restrict__ topv,
    float* __restrict__ topi)
{
    const int l = threadIdx.x & 63;
    const int t = (int)((blockIdx.x * 256u + threadIdx.x) >> 6);

    const int myid = cand[(size_t)t * NCAND + (l & 15)];

    // x row: lane l covers k in {i*256 + l*4 + j}, coalesced 1KB/instr
    f32x4 xr[8];
    const float* xrow = x + (size_t)t * HDIM;
#pragma unroll
    for (int i = 0; i < 8; ++i)
        xr[i] = *reinterpret_cast<const f32x4*>(xrow + i * 256 + l * 4);

    double vref = 0.0;
    for (int c = 0; c < NCAND; ++c) {
        const int eid = __shfl(myid, c);   // lane c holds candidate c's id
        const float* wrow = w + (size_t)eid * HDIM;
        f32x4 wr[8];
#pragma unroll
        for (int i = 0; i < 8; ++i)
            wr[i] = *reinterpret_cast<const f32x4*>(wrow + i * 256 + l * 4);
        double d = 0.0;
#pragma unroll
        for (int i = 0; i < 8; ++i)
#pragma unroll
            for (int j = 0; j < 4; ++j)
                d = fma((double)xr[i][j], (double)wr[i][j], d);
#pragma unroll
        for (int off = 32; off > 0; off >>= 1)
            d += __shfl_xor(d, off);
        if (l == c) vref = d;
    }

    // exact top-8 among the 16 refined values (lanes 0..15), id tie-break
    const double NEGD = -__builtin_inf();
    bool sel = false;
    double m = 0.0, kv = 0.0;
    int ki = 0;
#pragma unroll
    for (int k = 0; k < KSEL; ++k) {
        double cv = sel ? NEGD : ((l & 48) ? NEGD : vref);  // lanes >=16 inert
        int ce = myid;
#pragma unroll
        for (int off = 8; off > 0; off >>= 1) {
            const double ov = __shfl_xor(cv, off, 16);
            const int    oe = __shfl_xor(ce, off, 16);
            if (ov > cv || (ov == cv && oe < ce)) { cv = ov; ce = oe; }
        }
        if (k == 0) m = cv;
        if ((l & 15) == k) { kv = cv; ki = ce; }
        if (ce == myid) sel = true;
    }

    float p = ((l & 15) < KSEL) ? expf((float)(kv - m)) : 0.0f;
    float ps = p;
#pragma unroll
    for (int off = 8; off > 0; off >>= 1)
        ps += __shfl_xor(ps, off, 16);

    if (l < KSEL) {
        topv[(size_t)t * KSEL + l] = p / ps;
        topi[(size_t)t * KSEL + l] = (float)ki;
    }
}

// ===========================================================================
// Fallback (ws too small): proven round-2 fused fp64 kernel.
// ===========================================================================
#define BM 64
#define BK 32
#define BSTRIDE (BK + 4)
__global__ __launch_bounds__(256) void router_fused(
    const float* __restrict__ x, const float* __restrict__ w,
    float* __restrict__ logits, float* __restrict__ topv, float* __restrict__ topi)
{
    __shared__ float Bs[NEXP][BSTRIDE];
    const int tid = threadIdx.x;
    const int tn = tid & 15, tm = tid >> 4;
    const int row0 = blockIdx.x * BM;
    const int kc = tid & 7, cr = tid >> 3;

    double acc[4][8];
#pragma unroll
    for (int i = 0; i < 4; ++i)
#pragma unroll
        for (int j = 0; j < 8; ++j) acc[i][j] = 0.0;

    const float* xp[4];
#pragma unroll
    for (int i = 0; i < 4; ++i) xp[i] = x + (size_t)(row0 + tm + 16 * i) * HDIM;

    float4 rb[4];
#pragma unroll
    for (int p = 0; p < 4; ++p)
        rb[p] = *reinterpret_cast<const float4*>(&w[(size_t)(cr + 32 * p) * HDIM + kc * 4]);

    for (int k0 = 0; k0 < HDIM; k0 += BK) {
        __syncthreads();
#pragma unroll
        for (int p = 0; p < 4; ++p)
            *reinterpret_cast<float4*>(&Bs[cr + 32 * p][kc * 4]) = rb[p];
        __syncthreads();
        if (k0 + BK < HDIM) {
#pragma unroll
            for (int p = 0; p < 4; ++p)
                rb[p] = *reinterpret_cast<const float4*>(
                    &w[(size_t)(cr + 32 * p) * HDIM + (k0 + BK) + kc * 4]);
        }
#pragma unroll 4
        for (int k4 = 0; k4 < BK; k4 += 4) {
            float4 a4[4], b4[8];
#pragma unroll
            for (int i = 0; i < 4; ++i)
                a4[i] = *reinterpret_cast<const float4*>(&xp[i][k0 + k4]);
#pragma unroll
            for (int j = 0; j < 8; ++j)
                b4[j] = *reinterpret_cast<const float4*>(&Bs[tn + 16 * j][k4]);
#pragma unroll
            for (int kk = 0; kk < 4; ++kk) {
                double bd[8];
#pragma unroll
                for (int j = 0; j < 8; ++j) bd[j] = (double)((const float*)&b4[j])[kk];
#pragma unroll
                for (int i = 0; i < 4; ++i) {
                    const double ad = (double)((const float*)&a4[i])[kk];
#pragma unroll
                    for (int j = 0; j < 8; ++j) acc[i][j] = fma(ad, bd[j], acc[i][j]);
                }
            }
        }
    }
#pragma unroll
    for (int i = 0; i < 4; ++i) {
        float* orow = logits + (size_t)(row0 + tm + 16 * i) * NEXP;
#pragma unroll
        for (int j = 0; j < 8; ++j) orow[tn + 16 * j] = (float)acc[i][j];
    }
    for (int i = 0; i < 4; ++i) {
        const int t = row0 + tm + 16 * i;
        unsigned sel = 0u;
        double m = 0.0, kv = 0.0;
        int ki = 0;
        const double NEGD = -__builtin_inf();
#pragma unroll
        for (int k = 0; k < KSEL; ++k) {
            double lv = NEGD; int le = 0;
#pragma unroll
            for (int j = 0; j < 8; ++j) {
                const double v = (sel >> j) & 1u ? NEGD : acc[i][j];
                if (v > lv) { lv = v; le = tn + 16 * j; }
            }
            double cv = lv; int ce = le;
#pragma unroll
            for (int off = 8; off > 0; off >>= 1) {
                const double ov = __shfl_xor(cv, off, 16);
                const int    oe = __shfl_xor(ce, off, 16);
                if (ov > cv || (ov == cv && oe < ce)) { cv = ov; ce = oe; }
            }
            if (k == 0) m = cv;
            if (tn == k) { kv = cv; ki = ce; }
            if ((ce & 15) == tn) sel |= 1u << (ce >> 4);
        }
        float z = 0.0f;
#pragma unroll
        for (int j = 0; j < 8; ++j) z += expf((float)(acc[i][j] - m));
#pragma unroll
        for (int off = 8; off > 0; off >>= 1) z += __shfl_xor(z, off, 16);
        const float p = (tn < KSEL) ? expf((float)(kv - m)) / z : 0.0f;
        float ps = p;
#pragma unroll
        for (int off = 8; off > 0; off >>= 1) ps += __shfl_xor(ps, off, 16);
        if (tn < KSEL) {
            topv[(size_t)t * KSEL + tn] = p / ps;
            topi[(size_t)t * KSEL + tn] = (float)ki;
        }
    }
}

extern "C" void kernel_launch(void* const* d_in, const int* in_sizes, int n_in,
                              void* d_out, int out_size, void* d_ws, size_t ws_size,
                              hipStream_t stream) {
    const float* x = (const float*)d_in[0];   // [16384, 2048]
    const float* w = (const float*)d_in[1];   // [128, 2048]

    float* out    = (float*)d_out;
    float* logits = out;                                   // 16384*128
    float* topv   = out + (size_t)NTOK * NEXP;             // 16384*8
    float* topi   = topv + (size_t)NTOK * KSEL;            // 16384*8

    const size_t need = (size_t)NTOK * NCAND * sizeof(int);  // 1 MB
    if (ws_size >= need) {
        int* cand = (int*)d_ws;
        gemm_select<<<NTOK / 64, 256, 0, stream>>>(x, w, logits, cand);
        refine_topk<<<NTOK / 4, 256, 0, stream>>>(x, w, cand, topv, topi);
    } else {
        router_fused<<<NTOK / BM, 256, 0, stream>>>(x, w, logits, topv, topi);
    }
}

// Round 5
// 130.228 us; speedup vs baseline: 4.5621x; 1.1834x over previous
//
#include <hip/hip_runtime.h>
#include <hip/hip_bf16.h>
#include <hip/hip_fp16.h>

#define NTOK 16384
#define HDIM 2048
#define NEXP 128
#define KSEL 8
#define NCAND 16
#define DELTA_GAP 1e-4f     // certify gap > DELTA; err_ours(5sig)~4e-6, err_np(5sig)~2.5e-5
#define LO_SCALE 2048.0f    // 2^11: keeps lo-planes in fp16 normal range (raw wl ~1e-5 is denormal!)
#define LO_INV (1.0f/2048.0f)

typedef _Float16 half8  __attribute__((ext_vector_type(8)));
typedef _Float16 half4v __attribute__((ext_vector_type(4)));
typedef float    f32x4  __attribute__((ext_vector_type(4)));

// ===========================================================================
// Kernel 1: split-fp16 3-product MFMA GEMM (logit err ~1e-6) + full top-8
// output + gap certification. Block = 64 tokens x 128 experts, 256 thr
// (4 waves, wave = 16 tok x 128 exp). LDS 48KB single-buffer, fragment-major
// (lane l's 16B frag at l*8 halfwords): regions xh[0]|xl[4096]|wh[8192]|wl[16384].
// acc (hh) + acc2 (xh*wl' + xl'*wh, scaled 2^11); logit = acc + acc2/2048.
// Per token: top-16 candidates; ranks 0..8 adjacent gaps < DELTA -> flag for
// fp64 refine (expected ~300 of 16384 tokens).
// ===========================================================================
__global__ __launch_bounds__(256) void gemm3_select(
    const float* __restrict__ x, const float* __restrict__ w,
    float* __restrict__ logits, float* __restrict__ topv, float* __restrict__ topi,
    int* __restrict__ cand, int* __restrict__ flag)
{
    __shared__ _Float16 sm[24576];   // 48 KB

    const int tid = threadIdx.x;
    const int l   = tid & 63;
    const int wv  = tid >> 6;
    const int t0  = blockIdx.x * 64;

    // ---- staging maps (proven in round 4) ----
    const int tl = tid >> 2;                       // x row 0..63
    const float* xrow = x + (size_t)(t0 + tl) * HDIM;
    int kqx[4], idxX[4];
#pragma unroll
    for (int p = 0; p < 4; ++p) {
        const int k = 4 * (tid & 3) + 16 * p;
        kqx[p] = k;
        idxX[p] = (tl >> 4) * 1024 + (k >> 5) * 512
                + ((tl & 15) + 16 * ((k >> 3) & 3)) * 8 + (k & 7);
    }
    const int e = tid >> 1;                        // w row 0..127
    const float* wrow = w + (size_t)e * HDIM;
    int kqw[8], idxW[8];
#pragma unroll
    for (int q = 0; q < 8; ++q) {
        const int k = 4 * (tid & 1) + 8 * q;
        kqw[q] = k;
        idxW[q] = 8192 + (e >> 4) * 1024 + (k >> 5) * 512
                + ((e & 15) + 16 * ((k >> 3) & 3)) * 8 + (k & 7);
    }

    f32x4 acc[8], acc2[8];
#pragma unroll
    for (int f = 0; f < 8; ++f) {
        acc[f]  = (f32x4){0.f, 0.f, 0.f, 0.f};
        acc2[f] = (f32x4){0.f, 0.f, 0.f, 0.f};
    }

    // prologue: step-0 loads
    f32x4 xa[4], wr[8];
#pragma unroll
    for (int p = 0; p < 4; ++p) xa[p] = *reinterpret_cast<const f32x4*>(xrow + kqx[p]);
#pragma unroll
    for (int q = 0; q < 8; ++q) wr[q] = *reinterpret_cast<const f32x4*>(wrow + kqw[q]);

    for (int s = 0; s < 32; ++s) {
        __syncthreads();   // prior step's LDS reads done

        // ---- stage hi/lo planes ----
#pragma unroll
        for (int p = 0; p < 4; ++p) {
            half4v h, lo;
#pragma unroll
            for (int j = 0; j < 4; ++j) {
                const _Float16 hj = (_Float16)xa[p][j];
                h[j]  = hj;
                lo[j] = (_Float16)((xa[p][j] - (float)hj) * LO_SCALE);
            }
            *reinterpret_cast<half4v*>(&sm[idxX[p]])        = h;
            *reinterpret_cast<half4v*>(&sm[idxX[p] + 4096]) = lo;
        }
#pragma unroll
        for (int q = 0; q < 8; ++q) {
            half4v h, lo;
#pragma unroll
            for (int j = 0; j < 4; ++j) {
                const _Float16 hj = (_Float16)wr[q][j];
                h[j]  = hj;
                lo[j] = (_Float16)((wr[q][j] - (float)hj) * LO_SCALE);
            }
            *reinterpret_cast<half4v*>(&sm[idxW[q]])        = h;
            *reinterpret_cast<half4v*>(&sm[idxW[q] + 8192]) = lo;
        }

        __syncthreads();

        // prefetch next step (in flight during MFMA)
        if (s + 1 < 32) {
            const int kb = (s + 1) * 64;
#pragma unroll
            for (int p = 0; p < 4; ++p)
                xa[p] = *reinterpret_cast<const f32x4*>(xrow + kb + kqx[p]);
#pragma unroll
            for (int q = 0; q < 8; ++q)
                wr[q] = *reinterpret_cast<const f32x4*>(wrow + kb + kqw[q]);
        }

        const _Float16* xbh = &sm[wv * 1024 + l * 8];
        const _Float16* wbh = &sm[8192 + l * 8];
#pragma unroll
        for (int kh = 0; kh < 2; ++kh) {
            const half8 ah = *reinterpret_cast<const half8*>(xbh + kh * 512);
            const half8 al = *reinterpret_cast<const half8*>(xbh + 4096 + kh * 512);
#pragma unroll
            for (int f = 0; f < 8; ++f) {
                const half8 bh = *reinterpret_cast<const half8*>(wbh + f * 1024 + kh * 512);
                const half8 bl = *reinterpret_cast<const half8*>(wbh + 8192 + f * 1024 + kh * 512);
                acc[f]  = __builtin_amdgcn_mfma_f32_16x16x32_f16(ah, bh, acc[f],  0, 0, 0);
                acc2[f] = __builtin_amdgcn_mfma_f32_16x16x32_f16(ah, bl, acc2[f], 0, 0, 0);
                acc2[f] = __builtin_amdgcn_mfma_f32_16x16x32_f16(al, bh, acc2[f], 0, 0, 0);
            }
        }
    }

    // ---- per-token epilogue: logits, top-16, gaps, probs ----
    const int grp  = l >> 4;
    const int ln16 = l & 15;
    const float NEG = -__builtin_inff();

    for (int r = 0; r < 4; ++r) {
        const int t = t0 + wv * 16 + 4 * grp + r;
        float v[8];
#pragma unroll
        for (int f = 0; f < 8; ++f) {
            v[f] = acc[f][r] + acc2[f][r] * LO_INV;
            logits[(size_t)t * NEXP + 16 * f + ln16] = v[f];
        }

        unsigned selm = 0u;
        int   mycand = 0;
        float mycv   = 0.0f;
#pragma unroll
        for (int k = 0; k < NCAND; ++k) {
            float lv = NEG; int le = 0;
#pragma unroll
            for (int f = 0; f < 8; ++f) {
                const float c = ((selm >> f) & 1u) ? NEG : v[f];
                if (c > lv) { lv = c; le = 16 * f + ln16; }   // asc f => lower id on tie
            }
            float cv = lv; int ce = le;
#pragma unroll
            for (int off = 8; off > 0; off >>= 1) {
                const float ov = __shfl_xor(cv, off, 16);
                const int   oe = __shfl_xor(ce, off, 16);
                if (ov > cv || (ov == cv && oe < ce)) { cv = ov; ce = oe; }
            }
            if (ln16 == k) { mycand = ce; mycv = cv; }
            if ((ce & 15) == ln16) selm |= 1u << (ce >> 4);
        }

        // gap certification over ranks 0..8 (9 adjacent gaps)
        const float nv = __shfl(mycv, ln16 + 1, 16);
        int fl = (ln16 <= 8 && (mycv - nv) < DELTA_GAP) ? 1 : 0;
#pragma unroll
        for (int off = 8; off > 0; off >>= 1)
            fl |= __shfl_xor(fl, off, 16);

        // normalized top-8 probs (softmax denom cancels in renorm)
        const float m = __shfl(mycv, 0, 16);
        const float p = (ln16 < KSEL) ? expf(mycv - m) : 0.0f;
        float ps = p;
#pragma unroll
        for (int off = 8; off > 0; off >>= 1)
            ps += __shfl_xor(ps, off, 16);

        cand[(size_t)t * NCAND + ln16] = mycand;
        if (ln16 < KSEL) {
            topv[(size_t)t * KSEL + ln16] = p / ps;
            topi[(size_t)t * KSEL + ln16] = (float)mycand;
        }
        if (ln16 == 0) flag[t] = fl;
    }
}

// ===========================================================================
// Kernel 2: fp64 refine of flagged tokens only (~300 expected). One wave per
// token; unflagged waves exit at the flag read. Hoisted x->double (cvt once),
// 16 partials then ILP butterfly (fp-commutative => bitwise-identical sums in
// all lanes), redundant register top-8 (no shuffles in selection).
// ===========================================================================
__global__ __launch_bounds__(256) void refine_flagged(
    const float* __restrict__ x, const float* __restrict__ w,
    const int* __restrict__ cand, const int* __restrict__ flag,
    float* __restrict__ topv, float* __restrict__ topi)
{
    const int l = threadIdx.x & 63;
    const int t = (int)((blockIdx.x * 256u + threadIdx.x) >> 6);
    if (!flag[t]) return;   // wave-uniform

    const int myid = cand[(size_t)t * NCAND + (l & 15)];
    const float* xrow = x + (size_t)t * HDIM;

    double xd[32];
#pragma unroll
    for (int i = 0; i < 8; ++i) {
        const f32x4 xv = *reinterpret_cast<const f32x4*>(xrow + i * 256 + l * 4);
#pragma unroll
        for (int j = 0; j < 4; ++j) xd[i * 4 + j] = (double)xv[j];
    }

    double part[NCAND];
    int    cid[NCAND];
#pragma unroll
    for (int c = 0; c < NCAND; ++c) {
        const int eid = __shfl(myid, c);   // lane c holds candidate c
        cid[c] = eid;
        const float* wrow = w + (size_t)eid * HDIM;
        double s = 0.0;
#pragma unroll
        for (int i = 0; i < 8; ++i) {
            const f32x4 wv4 = *reinterpret_cast<const f32x4*>(wrow + i * 256 + l * 4);
#pragma unroll
            for (int j = 0; j < 4; ++j)
                s = fma(xd[i * 4 + j], (double)wv4[j], s);
        }
        part[c] = s;
    }

#pragma unroll
    for (int off = 32; off > 0; off >>= 1)
#pragma unroll
        for (int c = 0; c < NCAND; ++c)
            part[c] += __shfl_xor(part[c], off);

    // redundant per-lane top-8 (identical in every lane)
    unsigned selm = 0u;
    double m = 0.0, kv = 0.0;
    int ki = 0;
    float psum = 0.0f;
#pragma unroll
    for (int k = 0; k < KSEL; ++k) {
        double bv = -__builtin_inf(); int bi = 0x7fffffff; int bc = 0;
#pragma unroll
        for (int c = 0; c < NCAND; ++c) {
            if (!((selm >> c) & 1u)) {
                if (part[c] > bv || (part[c] == bv && cid[c] < bi)) {
                    bv = part[c]; bi = cid[c]; bc = c;
                }
            }
        }
        if (k == 0) m = bv;
        psum += expf((float)(bv - m));
        if (l == k) { kv = bv; ki = bi; }
        selm |= 1u << bc;
    }

    if (l < KSEL) {
        topv[(size_t)t * KSEL + l] = expf((float)(kv - m)) / psum;
        topi[(size_t)t * KSEL + l] = (float)ki;
    }
}

// ===========================================================================
// Fallback (ws too small): proven round-2 fused fp64 kernel.
// ===========================================================================
#define BM 64
#define BK 32
#define BSTRIDE (BK + 4)
__global__ __launch_bounds__(256) void router_fused(
    const float* __restrict__ x, const float* __restrict__ w,
    float* __restrict__ logits, float* __restrict__ topv, float* __restrict__ topi)
{
    __shared__ float Bs[NEXP][BSTRIDE];
    const int tid = threadIdx.x;
    const int tn = tid & 15, tm = tid >> 4;
    const int row0 = blockIdx.x * BM;
    const int kc = tid & 7, cr = tid >> 3;

    double acc[4][8];
#pragma unroll
    for (int i = 0; i < 4; ++i)
#pragma unroll
        for (int j = 0; j < 8; ++j) acc[i][j] = 0.0;

    const float* xp[4];
#pragma unroll
    for (int i = 0; i < 4; ++i) xp[i] = x + (size_t)(row0 + tm + 16 * i) * HDIM;

    float4 rb[4];
#pragma unroll
    for (int p = 0; p < 4; ++p)
        rb[p] = *reinterpret_cast<const float4*>(&w[(size_t)(cr + 32 * p) * HDIM + kc * 4]);

    for (int k0 = 0; k0 < HDIM; k0 += BK) {
        __syncthreads();
#pragma unroll
        for (int p = 0; p < 4; ++p)
            *reinterpret_cast<float4*>(&Bs[cr + 32 * p][kc * 4]) = rb[p];
        __syncthreads();
        if (k0 + BK < HDIM) {
#pragma unroll
            for (int p = 0; p < 4; ++p)
                rb[p] = *reinterpret_cast<const float4*>(
                    &w[(size_t)(cr + 32 * p) * HDIM + (k0 + BK) + kc * 4]);
        }
#pragma unroll 4
        for (int k4 = 0; k4 < BK; k4 += 4) {
            float4 a4[4], b4[8];
#pragma unroll
            for (int i = 0; i < 4; ++i)
                a4[i] = *reinterpret_cast<const float4*>(&xp[i][k0 + k4]);
#pragma unroll
            for (int j = 0; j < 8; ++j)
                b4[j] = *reinterpret_cast<const float4*>(&Bs[tn + 16 * j][k4]);
#pragma unroll
            for (int kk = 0; kk < 4; ++kk) {
                double bd[8];
#pragma unroll
                for (int j = 0; j < 8; ++j) bd[j] = (double)((const float*)&b4[j])[kk];
#pragma unroll
                for (int i = 0; i < 4; ++i) {
                    const double ad = (double)((const float*)&a4[i])[kk];
#pragma unroll
                    for (int j = 0; j < 8; ++j) acc[i][j] = fma(ad, bd[j], acc[i][j]);
                }
            }
        }
    }
#pragma unroll
    for (int i = 0; i < 4; ++i) {
        float* orow = logits + (size_t)(row0 + tm + 16 * i) * NEXP;
#pragma unroll
        for (int j = 0; j < 8; ++j) orow[tn + 16 * j] = (float)acc[i][j];
    }
    for (int i = 0; i < 4; ++i) {
        const int t = row0 + tm + 16 * i;
        unsigned sel = 0u;
        double m = 0.0, kv = 0.0;
        int ki = 0;
        const double NEGD = -__builtin_inf();
#pragma unroll
        for (int k = 0; k < KSEL; ++k) {
            double lv = NEGD; int le = 0;
#pragma unroll
            for (int j = 0; j < 8; ++j) {
                const double v = (sel >> j) & 1u ? NEGD : acc[i][j];
                if (v > lv) { lv = v; le = tn + 16 * j; }
            }
            double cv = lv; int ce = le;
#pragma unroll
            for (int off = 8; off > 0; off >>= 1) {
                const double ov = __shfl_xor(cv, off, 16);
                const int    oe = __shfl_xor(ce, off, 16);
                if (ov > cv || (ov == cv && oe < ce)) { cv = ov; ce = oe; }
            }
            if (k == 0) m = cv;
            if (tn == k) { kv = cv; ki = ce; }
            if ((ce & 15) == tn) sel |= 1u << (ce >> 4);
        }
        float z = 0.0f;
#pragma unroll
        for (int j = 0; j < 8; ++j) z += expf((float)(acc[i][j] - m));
#pragma unroll
        for (int off = 8; off > 0; off >>= 1) z += __shfl_xor(z, off, 16);
        const float p = (tn < KSEL) ? expf((float)(kv - m)) / z : 0.0f;
        float ps = p;
#pragma unroll
        for (int off = 8; off > 0; off >>= 1) ps += __shfl_xor(ps, off, 16);
        if (tn < KSEL) {
            topv[(size_t)t * KSEL + tn] = p / ps;
            topi[(size_t)t * KSEL + tn] = (float)ki;
        }
    }
}

extern "C" void kernel_launch(void* const* d_in, const int* in_sizes, int n_in,
                              void* d_out, int out_size, void* d_ws, size_t ws_size,
                              hipStream_t stream) {
    const float* x = (const float*)d_in[0];   // [16384, 2048]
    const float* w = (const float*)d_in[1];   // [128, 2048]

    float* out    = (float*)d_out;
    float* logits = out;                                   // 16384*128
    float* topv   = out + (size_t)NTOK * NEXP;             // 16384*8
    float* topi   = topv + (size_t)NTOK * KSEL;            // 16384*8

    const size_t need = (size_t)NTOK * NCAND * sizeof(int)   // cand: 1 MB
                      + (size_t)NTOK * sizeof(int);          // flag: 64 KB
    if (ws_size >= need) {
        int* cand = (int*)d_ws;
        int* flag = cand + (size_t)NTOK * NCAND;
        gemm3_select<<<NTOK / 64, 256, 0, stream>>>(x, w, logits, topv, topi, cand, flag);
        refine_flagged<<<NTOK / 4, 256, 0, stream>>>(x, w, cand, flag, topv, topi);
    } else {
        router_fused<<<NTOK / BM, 256, 0, stream>>>(x, w, logits, topv, topi);
    }
}